// Round 15
// baseline (116.424 us; speedup 1.0000x reference)
//
#include <hip/hip_runtime.h>
#include <math.h>

#define BB 64
#define LL 512
#define RR 512
#define DD 512
#define FC 100
#define FP 112
#define HH 60
#define BD (BB*DD)

typedef __attribute__((ext_vector_type(8))) short bf16x8;
typedef __attribute__((ext_vector_type(4))) float f32x4;

__device__ __forceinline__ unsigned short bf16rne(float x) {
  unsigned u = __float_as_uint(x);
  return (unsigned short)((u + 0x7fffu + ((u >> 16) & 1u)) >> 16);
}
__device__ __forceinline__ float bf16tof(unsigned short h) {
  return __uint_as_float((unsigned)h << 16);
}

// Raw barrier with lgkmcnt(0)-only drain: LDS ops sealed, global prefetch
// loads stay in flight across the barrier.
__device__ __forceinline__ void bar_lgkm() {
  asm volatile("s_waitcnt lgkmcnt(0)" ::: "memory");
  __builtin_amdgcn_s_barrier();
}

// Truncating hi/lo bf16 split of 2 floats, packed via v_perm_b32.
__device__ __forceinline__ void split2(float x0, float x1, unsigned& h2, unsigned& l2) {
  unsigned u0 = __float_as_uint(x0), u1 = __float_as_uint(x1);
  h2 = __builtin_amdgcn_perm(u1, u0, 0x07060302u);
  float r0 = x0 - __uint_as_float(u0 & 0xffff0000u);
  float r1 = x1 - __uint_as_float(u1 & 0xffff0000u);
  l2 = __builtin_amdgcn_perm(__float_as_uint(r1), __float_as_uint(r0), 0x07060302u);
}

// DPP row_ror reductions over the 16-lane DPP row (= fr lanes, fixed kh).
template <int N>
__device__ __forceinline__ float ror_max_f(float v) {
  return fmaxf(v, __uint_as_float(__builtin_amdgcn_mov_dpp(__float_as_uint(v), 0x120 | N, 0xf, 0xf, true)));
}
template <int N>
__device__ __forceinline__ float ror_add_f(float v) {
  return v + __uint_as_float(__builtin_amdgcn_mov_dpp(__float_as_uint(v), 0x120 | N, 0xf, 0xf, true));
}
template <int N>
__device__ __forceinline__ int ror_min_i(int v) {
  int o = __builtin_amdgcn_mov_dpp(v, 0x120 | N, 0xf, 0xf, true);
  return o < v ? o : v;
}
__device__ __forceinline__ float row16_max(float v) {
  v = ror_max_f<1>(v); v = ror_max_f<2>(v); v = ror_max_f<4>(v); return ror_max_f<8>(v);
}
__device__ __forceinline__ float row16_sum(float v) {
  v = ror_add_f<1>(v); v = ror_add_f<2>(v); v = ror_add_f<4>(v); return ror_add_f<8>(v);
}
__device__ __forceinline__ int row16_min(int v) {
  v = ror_min_i<1>(v); v = ror_min_i<2>(v); v = ror_min_i<4>(v); return ror_min_i<8>(v);
}

// ---------------- fused attention GEMM + softmax-stat partials ----------------
// (R14 config, measured 69.5-71 us: one-barrier dbuf, clamped unconditional
// prefetch, XOR swizzle, setprio.)  UNCHANGED this round.
__global__ __launch_bounds__(512, 2) void gemm_att(const float* __restrict__ lv,
                                                   const float* __restrict__ rv,
                                                   const int* __restrict__ llen,
                                                   const int* __restrict__ rlen,
                                                   float4* __restrict__ lpart,
                                                   float4* __restrict__ rpart) {
  __shared__ __align__(16) unsigned short Ah[2][256][32];
  __shared__ __align__(16) unsigned short Al[2][256][32];
  __shared__ __align__(16) unsigned short Bh[2][256][32];
  __shared__ __align__(16) unsigned short Bl[2][256][32];

  const int bid = blockIdx.x;
  const int wid = (bid & 7) * 32 + (bid >> 3);
  const int b  = wid >> 2;
  const int l0 = ((wid >> 1) & 1) * 256;
  const int r0 = (wid & 1) * 256;

  const int t = threadIdx.x;       // 0..511
  const int srow = t >> 1;         // 0..255
  const int half = t & 1;

  const float* Abase = lv + (size_t)(l0 + srow) * BD + b * DD + half * 16;
  const float* Bbase = rv + (size_t)(r0 + srow) * BD + b * DD + half * 16;

  const int sl0 = (((2 * half) ^ ((srow >> 1) & 3)) * 8);
  const int sl1 = (((2 * half + 1) ^ ((srow >> 1) & 3)) * 8);

  const int lane = t & 63;
  const int wv = t >> 6;           // 0..7
  const int wrow = wv >> 2;        // 0..1 -> 128-row l slice
  const int wcol = wv & 3;         // 0..3 -> 64-col r slice
  const int fr = lane & 15;
  const int kh = lane >> 4;        // 0..3
  const int koff = (kh ^ ((fr >> 1) & 3)) * 8;

  float4 pa[4], pb[4];

#define LOADCHUNK(n) { const int cn_ = ((n) < 15 ? (n) : 15) * 32; \
    const float* An = Abase + cn_; const float* Bn = Bbase + cn_; \
    pa[0] = *(const float4*)(An);     pa[1] = *(const float4*)(An + 4); \
    pa[2] = *(const float4*)(An + 8); pa[3] = *(const float4*)(An + 12); \
    pb[0] = *(const float4*)(Bn);     pb[1] = *(const float4*)(Bn + 4); \
    pb[2] = *(const float4*)(Bn + 8); pb[3] = *(const float4*)(Bn + 12); }

#define STAGE(nb) { unsigned h01, l01, h23, l23, h45, l45, h67, l67; \
    split2(pa[0].x, pa[0].y, h01, l01); split2(pa[0].z, pa[0].w, h23, l23); \
    split2(pa[1].x, pa[1].y, h45, l45); split2(pa[1].z, pa[1].w, h67, l67); \
    *(uint4*)&Ah[nb][srow][sl0] = make_uint4(h01, h23, h45, h67); \
    *(uint4*)&Al[nb][srow][sl0] = make_uint4(l01, l23, l45, l67); \
    split2(pa[2].x, pa[2].y, h01, l01); split2(pa[2].z, pa[2].w, h23, l23); \
    split2(pa[3].x, pa[3].y, h45, l45); split2(pa[3].z, pa[3].w, h67, l67); \
    *(uint4*)&Ah[nb][srow][sl1] = make_uint4(h01, h23, h45, h67); \
    *(uint4*)&Al[nb][srow][sl1] = make_uint4(l01, l23, l45, l67); \
    split2(pb[0].x, pb[0].y, h01, l01); split2(pb[0].z, pb[0].w, h23, l23); \
    split2(pb[1].x, pb[1].y, h45, l45); split2(pb[1].z, pb[1].w, h67, l67); \
    *(uint4*)&Bh[nb][srow][sl0] = make_uint4(h01, h23, h45, h67); \
    *(uint4*)&Bl[nb][srow][sl0] = make_uint4(l01, l23, l45, l67); \
    split2(pb[2].x, pb[2].y, h01, l01); split2(pb[2].z, pb[2].w, h23, l23); \
    split2(pb[3].x, pb[3].y, h45, l45); split2(pb[3].z, pb[3].w, h67, l67); \
    *(uint4*)&Bh[nb][srow][sl1] = make_uint4(h01, h23, h45, h67); \
    *(uint4*)&Bl[nb][srow][sl1] = make_uint4(l01, l23, l45, l67); }

#define COMPUTE(cb) { bf16x8 bh4[4], bl4[4]; \
    _Pragma("unroll") \
    for (int j = 0; j < 4; ++j) { \
      bh4[j] = *(const bf16x8*)&Bh[cb][wcol * 64 + j * 16 + fr][koff]; \
      bl4[j] = *(const bf16x8*)&Bl[cb][wcol * 64 + j * 16 + fr][koff]; \
    } \
    __builtin_amdgcn_s_setprio(1); \
    _Pragma("unroll") \
    for (int i = 0; i < 8; ++i) { \
      bf16x8 a_h = *(const bf16x8*)&Ah[cb][wrow * 128 + i * 16 + fr][koff]; \
      bf16x8 a_l = *(const bf16x8*)&Al[cb][wrow * 128 + i * 16 + fr][koff]; \
      _Pragma("unroll") \
      for (int j = 0; j < 4; ++j) { \
        acc[i][j] = __builtin_amdgcn_mfma_f32_16x16x32_bf16(a_h, bh4[j], acc[i][j], 0, 0, 0); \
        acc[i][j] = __builtin_amdgcn_mfma_f32_16x16x32_bf16(a_h, bl4[j], acc[i][j], 0, 0, 0); \
        acc[i][j] = __builtin_amdgcn_mfma_f32_16x16x32_bf16(a_l, bh4[j], acc[i][j], 0, 0, 0); \
      } \
    } \
    __builtin_amdgcn_s_setprio(0); }

  f32x4 acc[8][4];
#pragma unroll
  for (int i = 0; i < 8; ++i)
#pragma unroll
    for (int j = 0; j < 4; ++j) acc[i][j] = (f32x4){0.f, 0.f, 0.f, 0.f};

  LOADCHUNK(0);
  STAGE(0);
  LOADCHUNK(1);
  bar_lgkm();

  for (int p2 = 0; p2 < 8; ++p2) {
    const int c = p2 * 2;
    STAGE(1);
    LOADCHUNK(c + 2);
    COMPUTE(0);
    bar_lgkm();
    STAGE(0);
    LOADCHUNK(c + 3);
    COMPUTE(1);
    bar_lgkm();
  }

  // ================= fused stats epilogue =================
  const int ll_ = llen[b], rl_ = rlen[b];
  __syncthreads();
  float4* rowsc = (float4*)&Ah[0][0][0];
  float4* colsc = (float4*)&Bh[0][0][0];

  const int rbase = r0 + wcol * 64 + fr;
  bool vr4[4]; int rr4[4];
#pragma unroll
  for (int j = 0; j < 4; ++j) { rr4[j] = rbase + j * 16; vr4[j] = rr4[j] < rl_; }

#pragma unroll
  for (int i = 0; i < 8; ++i) {
#pragma unroll
    for (int q = 0; q < 4; ++q) {
      const int trow = wrow * 128 + i * 16 + kh * 4 + q;
      const bool vl = (l0 + trow) < ll_;
      float s[4];
      float M = -1e30f;
#pragma unroll
      for (int j = 0; j < 4; ++j) {
        float raw = acc[i][j][q];
        s[j] = !vr4[j] ? -10.f : (vl ? raw : 0.f);
        M = fmaxf(M, s[j]);
      }
      M = row16_max(M);
      float zv = 0.f, q2 = 0.f;
      int loc = 0x7fffffff;
#pragma unroll
      for (int j = 0; j < 4; ++j) {
        float e = __expf(s[j] - M);
        if (vr4[j]) {
          zv += e; q2 += e * e;
          if (s[j] == M && rr4[j] < loc) loc = rr4[j];
        }
      }
      zv = row16_sum(zv);
      q2 = row16_sum(q2);
      loc = row16_min(loc);
      if (fr == 0)
        rowsc[wcol * 256 + trow] = make_float4(M, zv, q2, __int_as_float(loc));
    }
  }

#pragma unroll
  for (int j = 0; j < 4; ++j) {
    const int tcol = wcol * 64 + j * 16 + fr;
    const bool vr = (r0 + tcol) < rl_;
    float M = -1e30f;
#pragma unroll
    for (int i = 0; i < 8; ++i)
#pragma unroll
      for (int q = 0; q < 4; ++q) {
        int lg = l0 + wrow * 128 + i * 16 + kh * 4 + q;
        bool vl = lg < ll_;
        float sv = !vl ? -10.f : (vr ? acc[i][j][q] : 0.f);
        M = fmaxf(M, sv);
      }
    M = fmaxf(M, __shfl_xor(M, 16, 64));
    M = fmaxf(M, __shfl_xor(M, 32, 64));
    float zv = 0.f, q2 = 0.f;
    int loc = 0x7fffffff;
#pragma unroll
    for (int i = 0; i < 8; ++i)
#pragma unroll
      for (int q = 0; q < 4; ++q) {
        int lg = l0 + wrow * 128 + i * 16 + kh * 4 + q;
        bool vl = lg < ll_;
        float sv = !vl ? -10.f : (vr ? acc[i][j][q] : 0.f);
        float e = __expf(sv - M);
        if (vl) {
          zv += e; q2 += e * e;
          if (sv == M && lg < loc) loc = lg;
        }
      }
    zv += __shfl_xor(zv, 16, 64); zv += __shfl_xor(zv, 32, 64);
    q2 += __shfl_xor(q2, 16, 64); q2 += __shfl_xor(q2, 32, 64);
    { int o = __shfl_xor(loc, 16, 64); loc = o < loc ? o : loc; }
    { int o = __shfl_xor(loc, 32, 64); loc = o < loc ? o : loc; }
    if (kh == 0)
      colsc[wrow * 256 + tcol] = make_float4(M, zv, q2, __int_as_float(loc));
  }

  __syncthreads();

  if (t < 256) {
    float4 p = rowsc[t];
    float M = p.x, zv = p.y, q2 = p.z;
    int loc = __float_as_int(p.w);
#pragma unroll
    for (int w2 = 1; w2 < 4; ++w2) {
      float4 o = rowsc[w2 * 256 + t];
      float M1 = o.x;
      float Mn = fmaxf(M, M1);
      float c0 = __expf(M - Mn), c1 = __expf(M1 - Mn);
      zv = zv * c0 + o.y * c1;
      q2 = q2 * c0 * c0 + o.z * c1 * c1;
      int loc1 = __float_as_int(o.w);
      loc = (M1 > M) ? loc1 : ((M1 == M && loc1 < loc) ? loc1 : loc);
      M = Mn;
    }
    lpart[((size_t)(b * 512 + l0 + t)) * 2 + (r0 >> 8)] =
        make_float4(M, zv, q2, __int_as_float(loc));
  } else {
    const int c = t - 256;
    float4 p = colsc[c];
    float M = p.x, zv = p.y, q2 = p.z;
    int loc = __float_as_int(p.w);
    {
      float4 o = colsc[256 + c];
      float M1 = o.x;
      float Mn = fmaxf(M, M1);
      float c0 = __expf(M - Mn), c1 = __expf(M1 - Mn);
      zv = zv * c0 + o.y * c1;
      q2 = q2 * c0 * c0 + o.z * c1 * c1;
      int loc1 = __float_as_int(o.w);
      loc = (M1 > M) ? loc1 : ((M1 == M && loc1 < loc) ? loc1 : loc);
      M = Mn;
    }
    rpart[((size_t)(b * 512 + r0 + c)) * 2 + (l0 >> 8)] =
        make_float4(M, zv, q2, __int_as_float(loc));
  }
#undef LOADCHUNK
#undef STAGE
#undef COMPUTE
}

// ---------------- merge 2 slice-partials per row/col -> final stats ----------------
__global__ __launch_bounds__(256) void stats_merge(const float4* __restrict__ lpart,
    const float4* __restrict__ rpart,
    const int* __restrict__ llen, const int* __restrict__ rlen,
    float* __restrict__ lwv, float* __restrict__ lan, int* __restrict__ lidx,
    float* __restrict__ rwv, float* __restrict__ ran, int* __restrict__ ridx) {
  const int gid = blockIdx.x * 256 + threadIdx.x;
  const int side = gid >> 15;
  const int pos = gid & 32767;
  const int b = pos >> 9, p = pos & 511;
  const float4* part = (side ? rpart : lpart) + (size_t)pos * 2;
  float4 P0 = part[0], P1 = part[1];
  float M = P0.x, zv = P0.y, q2 = P0.z;
  int loc = __float_as_int(P0.w);
  {
    float M1 = P1.x;
    float Mn = fmaxf(M, M1);
    float c0 = __expf(M - Mn), c1 = __expf(M1 - Mn);
    zv = zv * c0 + P1.y * c1;
    q2 = q2 * c0 * c0 + P1.z * c1 * c1;
    int loc1 = __float_as_int(P1.w);
    loc = (M1 > M) ? loc1 : ((M1 == M && loc1 < loc) ? loc1 : loc);
    M = Mn;
  }
  const int len = side ? llen[b] : rlen[b];
  const int own = side ? rlen[b] : llen[b];
  const int ninv = side ? (LL - llen[b]) : (RR - rlen[b]);
  float z0 = zv + (float)ninv * __expf(-10.f - M);
  float S = zv / z0;
  float inv = 1.f / (S + 1e-13f);
  float sumq = S * inv;
  float mean = sumq / (float)len;
  float sumq2 = q2 / (z0 * z0) * inv * inv;
  float var = sumq2 / (float)len - mean * mean;
  float wv = var / fmaxf(mean, 0.001f);
  float qmax = inv / z0;
  float an = qmax / fmaxf(qmax, 0.001f);
  int idx = (p < own && loc != 0x7fffffff) ? loc : 0;
  if (side == 0) { lwv[pos] = wv; lan[pos] = an; lidx[pos] = idx; }
  else           { rwv[pos] = wv; ran[pos] = an; ridx[pos] = idx; }
}

// ---------------- prep: Wconv [100][512] -> bf16 hi/lo [112][512] (f-major, zero-padded) ------
__global__ void prep_w(const float* __restrict__ Wconv,
                       unsigned short* __restrict__ Whg, unsigned short* __restrict__ Wlg) {
  int i = blockIdx.x * 256 + threadIdx.x;
  if (i < FP * DD) {
    int f = i >> 9;
    float w = (f < FC) ? Wconv[i] : 0.f;
    unsigned short h = bf16rne(w);
    unsigned short l = bf16rne(w - bf16tof(h));
    Whg[i] = h; Wlg[i] = l;
  }
}

// ---------------- conv + relu + masked maxpool via bf16 hi/lo MFMA ----------------
// R14 schedule ported: one-barrier double-buffered LDS, unconditional clamped
// prefetch (x, y-gather, W), XOR slot swizzle, setprio around MFMA.
__global__ __launch_bounds__(256, 2) void conv_pool_mfma(const float* __restrict__ lv,
    const float* __restrict__ rv,
    const float* __restrict__ lwv, const float* __restrict__ lan, const int* __restrict__ lidx,
    const float* __restrict__ rwv, const float* __restrict__ ran, const int* __restrict__ ridx,
    const int* __restrict__ llen, const int* __restrict__ rlen,
    const unsigned short* __restrict__ Whg, const unsigned short* __restrict__ Wlg,
    const float* __restrict__ bconv, float* __restrict__ feat) {
  __shared__ __align__(16) unsigned short Ah[2][128][32];
  __shared__ __align__(16) unsigned short Al[2][128][32];
  __shared__ __align__(16) unsigned short Wh[2][FP][32];
  __shared__ __align__(16) unsigned short Wl[2][FP][32];
  __shared__ float pool[4][FP];
  __shared__ float ppw[128], ppa[128];
  __shared__ int   ppi[128], ppv[128];

  const int bid = blockIdx.x;
  const int wid = (bid & 7) * 64 + (bid >> 3);
  const int side = wid >> 8;
  const int b    = (wid >> 2) & 63;
  const int s0   = (wid & 3) * 128;

  const int t = threadIdx.x;
  const float* x; const float* y; const float* wb; const float* ab; const int* ib; int plen;
  if (side == 0) { x = lv; y = rv; wb = lwv; ab = lan; ib = lidx; plen = llen[b]; }
  else           { x = rv; y = lv; wb = rwv; ab = ran; ib = ridx; plen = rlen[b]; }

  if (t < 128) {
    int pos = s0 + t;
    ppw[t] = wb[b * 512 + pos];
    ppa[t] = ab[b * 512 + pos];
    ppi[t] = ib[b * 512 + pos];
    ppv[t] = (pos < plen) ? 1 : 0;
  }
  __syncthreads();

  const int pos  = t >> 1;
  const int half = t & 1;
  const float w_ = ppw[pos];
  const float a_ = ppa[pos];
  const int   yi = ppi[pos];
  const float* xp = x + (size_t)(s0 + pos) * BD + b * DD + half * 16;
  const float* yp = y + (size_t)yi * BD + b * DD + half * 16;

  // A write slots (swizzled; same verified pattern as gemm)
  const int asl0 = (((2 * half) ^ ((pos >> 1) & 3)) * 8);
  const int asl1 = (((2 * half + 1) ^ ((pos >> 1) & 3)) * 8);

  // W roles: thread covers quarters idx0=t and idx1 (full 0..447 coverage;
  // t>=192 duplicates its own idx -> unconditional loads, benign dup store)
  const int idx1 = (t < 192) ? t + 256 : t;
  const int f0 = t >> 2,   q0 = t & 3;
  const int f1 = idx1 >> 2, q1 = idx1 & 3;
  const int wsl0 = ((q0 ^ ((f0 >> 1) & 3)) * 8);
  const int wsl1 = ((q1 ^ ((f1 >> 1) & 3)) * 8);

  const int lane = t & 63;
  const int wvi = t >> 6;        // wave 0..3
  const int m0 = wvi * 32;
  const int fr = lane & 15;
  const int kh = lane >> 4;
  const int koff = (kh ^ ((fr >> 1) & 3)) * 8;

  float4 xv[4], yv[4];
  uint4 w0h, w0l, w1h, w1l;

#define LOADX(n) { const int off = ((n) < 15 ? (n) : 15) * 32; \
    xv[0] = *(const float4*)(xp + off);      xv[1] = *(const float4*)(xp + off + 4); \
    xv[2] = *(const float4*)(xp + off + 8);  xv[3] = *(const float4*)(xp + off + 12); \
    yv[0] = *(const float4*)(yp + off);      yv[1] = *(const float4*)(yp + off + 4); \
    yv[2] = *(const float4*)(yp + off + 8);  yv[3] = *(const float4*)(yp + off + 12); }

#define LOADW(n) { const int off = ((n) < 15 ? (n) : 15) * 32; \
    w0h = *(const uint4*)&Whg[f0 * DD + off + q0 * 8]; \
    w0l = *(const uint4*)&Wlg[f0 * DD + off + q0 * 8]; \
    w1h = *(const uint4*)&Whg[f1 * DD + off + q1 * 8]; \
    w1l = *(const uint4*)&Wlg[f1 * DD + off + q1 * 8]; }

#define STAGEA(nb) { \
    float d0 = w_ * fabsf(xv[0].x - a_ * yv[0].x); \
    float d1 = w_ * fabsf(xv[0].y - a_ * yv[0].y); \
    float d2 = w_ * fabsf(xv[0].z - a_ * yv[0].z); \
    float d3 = w_ * fabsf(xv[0].w - a_ * yv[0].w); \
    float d4 = w_ * fabsf(xv[1].x - a_ * yv[1].x); \
    float d5 = w_ * fabsf(xv[1].y - a_ * yv[1].y); \
    float d6 = w_ * fabsf(xv[1].z - a_ * yv[1].z); \
    float d7 = w_ * fabsf(xv[1].w - a_ * yv[1].w); \
    unsigned h01, l01, h23, l23, h45, l45, h67, l67; \
    split2(d0, d1, h01, l01); split2(d2, d3, h23, l23); \
    split2(d4, d5, h45, l45); split2(d6, d7, h67, l67); \
    *(uint4*)&Ah[nb][pos][asl0] = make_uint4(h01, h23, h45, h67); \
    *(uint4*)&Al[nb][pos][asl0] = make_uint4(l01, l23, l45, l67); \
    d0 = w_ * fabsf(xv[2].x - a_ * yv[2].x); \
    d1 = w_ * fabsf(xv[2].y - a_ * yv[2].y); \
    d2 = w_ * fabsf(xv[2].z - a_ * yv[2].z); \
    d3 = w_ * fabsf(xv[2].w - a_ * yv[2].w); \
    d4 = w_ * fabsf(xv[3].x - a_ * yv[3].x); \
    d5 = w_ * fabsf(xv[3].y - a_ * yv[3].y); \
    d6 = w_ * fabsf(xv[3].z - a_ * yv[3].z); \
    d7 = w_ * fabsf(xv[3].w - a_ * yv[3].w); \
    split2(d0, d1, h01, l01); split2(d2, d3, h23, l23); \
    split2(d4, d5, h45, l45); split2(d6, d7, h67, l67); \
    *(uint4*)&Ah[nb][pos][asl1] = make_uint4(h01, h23, h45, h67); \
    *(uint4*)&Al[nb][pos][asl1] = make_uint4(l01, l23, l45, l67); }

#define STAGEW(nb) { \
    *(uint4*)&Wh[nb][f0][wsl0] = w0h; *(uint4*)&Wl[nb][f0][wsl0] = w0l; \
    *(uint4*)&Wh[nb][f1][wsl1] = w1h; *(uint4*)&Wl[nb][f1][wsl1] = w1l; }

#define COMPUTEC(cb) { bf16x8 ah[2], al[2]; \
    _Pragma("unroll") \
    for (int i = 0; i < 2; ++i) { \
      ah[i] = *(const bf16x8*)&Ah[cb][m0 + i * 16 + fr][koff]; \
      al[i] = *(const bf16x8*)&Al[cb][m0 + i * 16 + fr][koff]; \
    } \
    __builtin_amdgcn_s_setprio(1); \
    _Pragma("unroll") \
    for (int j = 0; j < 7; ++j) { \
      bf16x8 bh = *(const bf16x8*)&Wh[cb][j * 16 + fr][koff]; \
      bf16x8 bl = *(const bf16x8*)&Wl[cb][j * 16 + fr][koff]; \
      _Pragma("unroll") \
      for (int i = 0; i < 2; ++i) { \
        acc[i][j] = __builtin_amdgcn_mfma_f32_16x16x32_bf16(ah[i], bh, acc[i][j], 0, 0, 0); \
        acc[i][j] = __builtin_amdgcn_mfma_f32_16x16x32_bf16(ah[i], bl, acc[i][j], 0, 0, 0); \
        acc[i][j] = __builtin_amdgcn_mfma_f32_16x16x32_bf16(al[i], bh, acc[i][j], 0, 0, 0); \
      } \
    } \
    __builtin_amdgcn_s_setprio(0); }

  f32x4 acc[2][7];
#pragma unroll
  for (int i = 0; i < 2; ++i)
#pragma unroll
    for (int j = 0; j < 7; ++j) acc[i][j] = (f32x4){0.f, 0.f, 0.f, 0.f};

  // prologue: chunk0 -> buf0; chunk1 -> regs
  LOADX(0); LOADW(0);
  STAGEA(0); STAGEW(0);
  LOADX(1); LOADW(1);
  bar_lgkm();

  for (int p2 = 0; p2 < 8; ++p2) {
    const int c = p2 * 2;
    // phase A: stage chunk c+1 -> buf1; load chunk c+2; compute buf0 (chunk c)
    STAGEA(1); STAGEW(1);
    LOADX(c + 2); LOADW(c + 2);
    COMPUTEC(0);
    bar_lgkm();
    // phase B: stage chunk c+2 -> buf0; load chunk c+3; compute buf1 (chunk c+1)
    STAGEA(0); STAGEW(0);
    LOADX(c + 3); LOADW(c + 3);
    COMPUTEC(1);
    bar_lgkm();
  }

  // epilogue: bias + relu + validity + maxpool
#pragma unroll
  for (int j = 0; j < 7; ++j) {
    int f = j * 16 + fr;
    float bcv = (f < FC) ? bconv[f] : 0.f;
    float vmax = -1e30f;
#pragma unroll
    for (int i = 0; i < 2; ++i) {
#pragma unroll
      for (int q = 0; q < 4; ++q) {
        int sl = m0 + i * 16 + kh * 4 + q;
        if (ppv[sl]) vmax = fmaxf(vmax, fmaxf(acc[i][j][q] + bcv, 0.f));
      }
    }
    vmax = fmaxf(vmax, __shfl_xor(vmax, 16, 64));
    vmax = fmaxf(vmax, __shfl_xor(vmax, 32, 64));
    if (lane < 16) pool[wvi][f] = vmax;
  }
  __syncthreads();
  if (t < FC) {
    float v = fmaxf(fmaxf(pool[0][t], pool[1][t]), fmaxf(pool[2][t], pool[3][t]));
    if (v > -1e29f) atomicMax((int*)&feat[b * 200 + side * FC + t], __float_as_int(v));
  }
#undef LOADX
#undef LOADW
#undef STAGEA
#undef STAGEW
#undef COMPUTEC
}

// ---------------- final dense [B,200] x [200,60] + relu ----------------
__global__ void dense_out(const float* __restrict__ feat, const float* __restrict__ Wd,
                          const float* __restrict__ bd, float* __restrict__ out) {
  int b = blockIdx.x, h = threadIdx.x;
  if (h < HH) {
    float s = bd[h];
    const float* fb = feat + b * 200;
    const float* wr = Wd + h * 200;
    for (int k = 0; k < 200; ++k) s += fb[k] * wr[k];
    out[b * HH + h] = fmaxf(s, 0.f);
  }
}

extern "C" void kernel_launch(void* const* d_in, const int* in_sizes, int n_in,
                              void* d_out, int out_size, void* d_ws, size_t ws_size,
                              hipStream_t stream) {
  (void)in_sizes; (void)n_in; (void)out_size; (void)ws_size;
  const int*   llen  = (const int*)d_in[0];
  const float* lv    = (const float*)d_in[1];
  const int*   rlen  = (const int*)d_in[2];
  const float* rv    = (const float*)d_in[3];
  const float* Wconv = (const float*)d_in[4];
  const float* bconv = (const float*)d_in[5];
  const float* Wd    = (const float*)d_in[6];
  const float* bd    = (const float*)d_in[7];
  float* out = (float*)d_out;
  char* ws = (char*)d_ws;
  size_t off = 0;
  unsigned short* Whg = (unsigned short*)(ws + off); off += (size_t)FP * DD * 2;
  unsigned short* Wlg = (unsigned short*)(ws + off); off += (size_t)FP * DD * 2;
  float4* lpart = (float4*)(ws + off); off += (size_t)BB * LL * 2 * 16;   // 1 MiB
  float4* rpart = (float4*)(ws + off); off += (size_t)BB * RR * 2 * 16;   // 1 MiB
  float* lwv = (float*)(ws + off); off += (size_t)BB * LL * 4;
  float* lan = (float*)(ws + off); off += (size_t)BB * LL * 4;
  int*   lidx= (int*)  (ws + off); off += (size_t)BB * LL * 4;
  float* rwv = (float*)(ws + off); off += (size_t)BB * RR * 4;
  float* ran = (float*)(ws + off); off += (size_t)BB * RR * 4;
  int*   ridx= (int*)  (ws + off); off += (size_t)BB * RR * 4;
  float* feat= (float*)(ws + off); off += (size_t)BB * 200 * 4;

  hipMemsetAsync(feat, 0, BB * 200 * 4, stream);
  prep_w<<<(FP * DD + 255) / 256, 256, 0, stream>>>(Wconv, Whg, Wlg);
  gemm_att<<<dim3(256), 512, 0, stream>>>(lv, rv, llen, rlen, lpart, rpart);
  stats_merge<<<dim3(256), 256, 0, stream>>>(lpart, rpart, llen, rlen,
                                             lwv, lan, lidx, rwv, ran, ridx);
  conv_pool_mfma<<<dim3(512), 256, 0, stream>>>(lv, rv, lwv, lan, lidx,
                                                rwv, ran, ridx, llen, rlen,
                                                Whg, Wlg, bconv, feat);
  dense_out<<<BB, 64, 0, stream>>>(feat, Wd, bd, out);
}

// Round 16
// 113.480 us; speedup vs baseline: 1.0259x; 1.0259x over previous
//
#include <hip/hip_runtime.h>
#include <math.h>

#define BB 64
#define LL 512
#define RR 512
#define DD 512
#define FC 100
#define FP 112
#define HH 60
#define BD (BB*DD)

typedef __attribute__((ext_vector_type(8))) short bf16x8;
typedef __attribute__((ext_vector_type(4))) float f32x4;

__device__ __forceinline__ unsigned short bf16rne(float x) {
  unsigned u = __float_as_uint(x);
  return (unsigned short)((u + 0x7fffu + ((u >> 16) & 1u)) >> 16);
}
__device__ __forceinline__ float bf16tof(unsigned short h) {
  return __uint_as_float((unsigned)h << 16);
}

// Raw barrier with lgkmcnt(0)-only drain: LDS ops sealed, global prefetch
// loads stay in flight across the barrier.
__device__ __forceinline__ void bar_lgkm() {
  asm volatile("s_waitcnt lgkmcnt(0)" ::: "memory");
  __builtin_amdgcn_s_barrier();
}

// Truncating hi/lo bf16 split of 2 floats, packed via v_perm_b32.
__device__ __forceinline__ void split2(float x0, float x1, unsigned& h2, unsigned& l2) {
  unsigned u0 = __float_as_uint(x0), u1 = __float_as_uint(x1);
  h2 = __builtin_amdgcn_perm(u1, u0, 0x07060302u);
  float r0 = x0 - __uint_as_float(u0 & 0xffff0000u);
  float r1 = x1 - __uint_as_float(u1 & 0xffff0000u);
  l2 = __builtin_amdgcn_perm(__float_as_uint(r1), __float_as_uint(r0), 0x07060302u);
}

// DPP row_ror reductions over the 16-lane DPP row (= fr lanes, fixed kh).
template <int N>
__device__ __forceinline__ float ror_max_f(float v) {
  return fmaxf(v, __uint_as_float(__builtin_amdgcn_mov_dpp(__float_as_uint(v), 0x120 | N, 0xf, 0xf, true)));
}
template <int N>
__device__ __forceinline__ float ror_add_f(float v) {
  return v + __uint_as_float(__builtin_amdgcn_mov_dpp(__float_as_uint(v), 0x120 | N, 0xf, 0xf, true));
}
template <int N>
__device__ __forceinline__ int ror_min_i(int v) {
  int o = __builtin_amdgcn_mov_dpp(v, 0x120 | N, 0xf, 0xf, true);
  return o < v ? o : v;
}
__device__ __forceinline__ float row16_max(float v) {
  v = ror_max_f<1>(v); v = ror_max_f<2>(v); v = ror_max_f<4>(v); return ror_max_f<8>(v);
}
__device__ __forceinline__ float row16_sum(float v) {
  v = ror_add_f<1>(v); v = ror_add_f<2>(v); v = ror_add_f<4>(v); return ror_add_f<8>(v);
}
__device__ __forceinline__ int row16_min(int v) {
  v = ror_min_i<1>(v); v = ror_min_i<2>(v); v = ror_min_i<4>(v); return ror_min_i<8>(v);
}

// ---------------- fused attention GEMM + softmax-stat partials ----------------
// (R14 config, measured 69.5-71 us — FROZEN.)
__global__ __launch_bounds__(512, 2) void gemm_att(const float* __restrict__ lv,
                                                   const float* __restrict__ rv,
                                                   const int* __restrict__ llen,
                                                   const int* __restrict__ rlen,
                                                   float4* __restrict__ lpart,
                                                   float4* __restrict__ rpart) {
  __shared__ __align__(16) unsigned short Ah[2][256][32];
  __shared__ __align__(16) unsigned short Al[2][256][32];
  __shared__ __align__(16) unsigned short Bh[2][256][32];
  __shared__ __align__(16) unsigned short Bl[2][256][32];

  const int bid = blockIdx.x;
  const int wid = (bid & 7) * 32 + (bid >> 3);
  const int b  = wid >> 2;
  const int l0 = ((wid >> 1) & 1) * 256;
  const int r0 = (wid & 1) * 256;

  const int t = threadIdx.x;       // 0..511
  const int srow = t >> 1;         // 0..255
  const int half = t & 1;

  const float* Abase = lv + (size_t)(l0 + srow) * BD + b * DD + half * 16;
  const float* Bbase = rv + (size_t)(r0 + srow) * BD + b * DD + half * 16;

  const int sl0 = (((2 * half) ^ ((srow >> 1) & 3)) * 8);
  const int sl1 = (((2 * half + 1) ^ ((srow >> 1) & 3)) * 8);

  const int lane = t & 63;
  const int wv = t >> 6;           // 0..7
  const int wrow = wv >> 2;        // 0..1 -> 128-row l slice
  const int wcol = wv & 3;         // 0..3 -> 64-col r slice
  const int fr = lane & 15;
  const int kh = lane >> 4;        // 0..3
  const int koff = (kh ^ ((fr >> 1) & 3)) * 8;

  float4 pa[4], pb[4];

#define LOADCHUNK(n) { const int cn_ = ((n) < 15 ? (n) : 15) * 32; \
    const float* An = Abase + cn_; const float* Bn = Bbase + cn_; \
    pa[0] = *(const float4*)(An);     pa[1] = *(const float4*)(An + 4); \
    pa[2] = *(const float4*)(An + 8); pa[3] = *(const float4*)(An + 12); \
    pb[0] = *(const float4*)(Bn);     pb[1] = *(const float4*)(Bn + 4); \
    pb[2] = *(const float4*)(Bn + 8); pb[3] = *(const float4*)(Bn + 12); }

#define STAGE(nb) { unsigned h01, l01, h23, l23, h45, l45, h67, l67; \
    split2(pa[0].x, pa[0].y, h01, l01); split2(pa[0].z, pa[0].w, h23, l23); \
    split2(pa[1].x, pa[1].y, h45, l45); split2(pa[1].z, pa[1].w, h67, l67); \
    *(uint4*)&Ah[nb][srow][sl0] = make_uint4(h01, h23, h45, h67); \
    *(uint4*)&Al[nb][srow][sl0] = make_uint4(l01, l23, l45, l67); \
    split2(pa[2].x, pa[2].y, h01, l01); split2(pa[2].z, pa[2].w, h23, l23); \
    split2(pa[3].x, pa[3].y, h45, l45); split2(pa[3].z, pa[3].w, h67, l67); \
    *(uint4*)&Ah[nb][srow][sl1] = make_uint4(h01, h23, h45, h67); \
    *(uint4*)&Al[nb][srow][sl1] = make_uint4(l01, l23, l45, l67); \
    split2(pb[0].x, pb[0].y, h01, l01); split2(pb[0].z, pb[0].w, h23, l23); \
    split2(pb[1].x, pb[1].y, h45, l45); split2(pb[1].z, pb[1].w, h67, l67); \
    *(uint4*)&Bh[nb][srow][sl0] = make_uint4(h01, h23, h45, h67); \
    *(uint4*)&Bl[nb][srow][sl0] = make_uint4(l01, l23, l45, l67); \
    split2(pb[2].x, pb[2].y, h01, l01); split2(pb[2].z, pb[2].w, h23, l23); \
    split2(pb[3].x, pb[3].y, h45, l45); split2(pb[3].z, pb[3].w, h67, l67); \
    *(uint4*)&Bh[nb][srow][sl1] = make_uint4(h01, h23, h45, h67); \
    *(uint4*)&Bl[nb][srow][sl1] = make_uint4(l01, l23, l45, l67); }

#define COMPUTE(cb) { bf16x8 bh4[4], bl4[4]; \
    _Pragma("unroll") \
    for (int j = 0; j < 4; ++j) { \
      bh4[j] = *(const bf16x8*)&Bh[cb][wcol * 64 + j * 16 + fr][koff]; \
      bl4[j] = *(const bf16x8*)&Bl[cb][wcol * 64 + j * 16 + fr][koff]; \
    } \
    __builtin_amdgcn_s_setprio(1); \
    _Pragma("unroll") \
    for (int i = 0; i < 8; ++i) { \
      bf16x8 a_h = *(const bf16x8*)&Ah[cb][wrow * 128 + i * 16 + fr][koff]; \
      bf16x8 a_l = *(const bf16x8*)&Al[cb][wrow * 128 + i * 16 + fr][koff]; \
      _Pragma("unroll") \
      for (int j = 0; j < 4; ++j) { \
        acc[i][j] = __builtin_amdgcn_mfma_f32_16x16x32_bf16(a_h, bh4[j], acc[i][j], 0, 0, 0); \
        acc[i][j] = __builtin_amdgcn_mfma_f32_16x16x32_bf16(a_h, bl4[j], acc[i][j], 0, 0, 0); \
        acc[i][j] = __builtin_amdgcn_mfma_f32_16x16x32_bf16(a_l, bh4[j], acc[i][j], 0, 0, 0); \
      } \
    } \
    __builtin_amdgcn_s_setprio(0); }

  f32x4 acc[8][4];
#pragma unroll
  for (int i = 0; i < 8; ++i)
#pragma unroll
    for (int j = 0; j < 4; ++j) acc[i][j] = (f32x4){0.f, 0.f, 0.f, 0.f};

  LOADCHUNK(0);
  STAGE(0);
  LOADCHUNK(1);
  bar_lgkm();

  for (int p2 = 0; p2 < 8; ++p2) {
    const int c = p2 * 2;
    STAGE(1);
    LOADCHUNK(c + 2);
    COMPUTE(0);
    bar_lgkm();
    STAGE(0);
    LOADCHUNK(c + 3);
    COMPUTE(1);
    bar_lgkm();
  }

  // ================= fused stats epilogue =================
  const int ll_ = llen[b], rl_ = rlen[b];
  __syncthreads();
  float4* rowsc = (float4*)&Ah[0][0][0];
  float4* colsc = (float4*)&Bh[0][0][0];

  const int rbase = r0 + wcol * 64 + fr;
  bool vr4[4]; int rr4[4];
#pragma unroll
  for (int j = 0; j < 4; ++j) { rr4[j] = rbase + j * 16; vr4[j] = rr4[j] < rl_; }

#pragma unroll
  for (int i = 0; i < 8; ++i) {
#pragma unroll
    for (int q = 0; q < 4; ++q) {
      const int trow = wrow * 128 + i * 16 + kh * 4 + q;
      const bool vl = (l0 + trow) < ll_;
      float s[4];
      float M = -1e30f;
#pragma unroll
      for (int j = 0; j < 4; ++j) {
        float raw = acc[i][j][q];
        s[j] = !vr4[j] ? -10.f : (vl ? raw : 0.f);
        M = fmaxf(M, s[j]);
      }
      M = row16_max(M);
      float zv = 0.f, q2 = 0.f;
      int loc = 0x7fffffff;
#pragma unroll
      for (int j = 0; j < 4; ++j) {
        float e = __expf(s[j] - M);
        if (vr4[j]) {
          zv += e; q2 += e * e;
          if (s[j] == M && rr4[j] < loc) loc = rr4[j];
        }
      }
      zv = row16_sum(zv);
      q2 = row16_sum(q2);
      loc = row16_min(loc);
      if (fr == 0)
        rowsc[wcol * 256 + trow] = make_float4(M, zv, q2, __int_as_float(loc));
    }
  }

#pragma unroll
  for (int j = 0; j < 4; ++j) {
    const int tcol = wcol * 64 + j * 16 + fr;
    const bool vr = (r0 + tcol) < rl_;
    float M = -1e30f;
#pragma unroll
    for (int i = 0; i < 8; ++i)
#pragma unroll
      for (int q = 0; q < 4; ++q) {
        int lg = l0 + wrow * 128 + i * 16 + kh * 4 + q;
        bool vl = lg < ll_;
        float sv = !vl ? -10.f : (vr ? acc[i][j][q] : 0.f);
        M = fmaxf(M, sv);
      }
    M = fmaxf(M, __shfl_xor(M, 16, 64));
    M = fmaxf(M, __shfl_xor(M, 32, 64));
    float zv = 0.f, q2 = 0.f;
    int loc = 0x7fffffff;
#pragma unroll
    for (int i = 0; i < 8; ++i)
#pragma unroll
      for (int q = 0; q < 4; ++q) {
        int lg = l0 + wrow * 128 + i * 16 + kh * 4 + q;
        bool vl = lg < ll_;
        float sv = !vl ? -10.f : (vr ? acc[i][j][q] : 0.f);
        float e = __expf(sv - M);
        if (vl) {
          zv += e; q2 += e * e;
          if (sv == M && lg < loc) loc = lg;
        }
      }
    zv += __shfl_xor(zv, 16, 64); zv += __shfl_xor(zv, 32, 64);
    q2 += __shfl_xor(q2, 16, 64); q2 += __shfl_xor(q2, 32, 64);
    { int o = __shfl_xor(loc, 16, 64); loc = o < loc ? o : loc; }
    { int o = __shfl_xor(loc, 32, 64); loc = o < loc ? o : loc; }
    if (kh == 0)
      colsc[wrow * 256 + tcol] = make_float4(M, zv, q2, __int_as_float(loc));
  }

  __syncthreads();

  if (t < 256) {
    float4 p = rowsc[t];
    float M = p.x, zv = p.y, q2 = p.z;
    int loc = __float_as_int(p.w);
#pragma unroll
    for (int w2 = 1; w2 < 4; ++w2) {
      float4 o = rowsc[w2 * 256 + t];
      float M1 = o.x;
      float Mn = fmaxf(M, M1);
      float c0 = __expf(M - Mn), c1 = __expf(M1 - Mn);
      zv = zv * c0 + o.y * c1;
      q2 = q2 * c0 * c0 + o.z * c1 * c1;
      int loc1 = __float_as_int(o.w);
      loc = (M1 > M) ? loc1 : ((M1 == M && loc1 < loc) ? loc1 : loc);
      M = Mn;
    }
    lpart[((size_t)(b * 512 + l0 + t)) * 2 + (r0 >> 8)] =
        make_float4(M, zv, q2, __int_as_float(loc));
  } else {
    const int c = t - 256;
    float4 p = colsc[c];
    float M = p.x, zv = p.y, q2 = p.z;
    int loc = __float_as_int(p.w);
    {
      float4 o = colsc[256 + c];
      float M1 = o.x;
      float Mn = fmaxf(M, M1);
      float c0 = __expf(M - Mn), c1 = __expf(M1 - Mn);
      zv = zv * c0 + o.y * c1;
      q2 = q2 * c0 * c0 + o.z * c1 * c1;
      int loc1 = __float_as_int(o.w);
      loc = (M1 > M) ? loc1 : ((M1 == M && loc1 < loc) ? loc1 : loc);
      M = Mn;
    }
    rpart[((size_t)(b * 512 + r0 + c)) * 2 + (l0 >> 8)] =
        make_float4(M, zv, q2, __int_as_float(loc));
  }
#undef LOADCHUNK
#undef STAGE
#undef COMPUTE
}

// ---------------- prep: Wconv [100][512] -> bf16 hi/lo [112][512] (f-major, zero-padded) ------
__global__ void prep_w(const float* __restrict__ Wconv,
                       unsigned short* __restrict__ Whg, unsigned short* __restrict__ Wlg) {
  int i = blockIdx.x * 256 + threadIdx.x;
  if (i < FP * DD) {
    int f = i >> 9;
    float w = (f < FC) ? Wconv[i] : 0.f;
    unsigned short h = bf16rne(w);
    unsigned short l = bf16rne(w - bf16tof(h));
    Whg[i] = h; Wlg[i] = l;
  }
}

// ---------------- conv + relu + masked maxpool via bf16 hi/lo MFMA ----------------
// Stats merge FUSED into prologue (reads lpart/rpart directly). Per-chunk pool
// results written to poolws (no atomics/memset). MFMA phase split around
// STAGE/LOAD so staging VALU interleaves with MFMA within each wave.
__global__ __launch_bounds__(256, 2) void conv_pool_mfma(const float* __restrict__ lv,
    const float* __restrict__ rv,
    const float4* __restrict__ lpart, const float4* __restrict__ rpart,
    const int* __restrict__ llen, const int* __restrict__ rlen,
    const unsigned short* __restrict__ Whg, const unsigned short* __restrict__ Wlg,
    const float* __restrict__ bconv, float* __restrict__ poolws) {
  __shared__ __align__(16) unsigned short Ah[2][128][32];
  __shared__ __align__(16) unsigned short Al[2][128][32];
  __shared__ __align__(16) unsigned short Wh[2][FP][32];
  __shared__ __align__(16) unsigned short Wl[2][FP][32];
  __shared__ float pool[4][FP];
  __shared__ float ppw[128], ppa[128];
  __shared__ int   ppi[128], ppv[128];

  const int bid = blockIdx.x;
  const int wid = (bid & 7) * 64 + (bid >> 3);
  const int side = wid >> 8;
  const int b    = (wid >> 2) & 63;
  const int s0   = (wid & 3) * 128;

  const int t = threadIdx.x;
  const int ll_b = llen[b], rl_b = rlen[b];
  const float* x; const float* y; int plen;
  if (side == 0) { x = lv; y = rv; plen = ll_b; }
  else           { x = rv; y = lv; plen = rl_b; }

  // fused stats merge (was stats_merge kernel): 2 slice-partials -> w, an, idx
  if (t < 128) {
    int pos = s0 + t;
    const float4* part = (side ? rpart : lpart) + (size_t)(b * 512 + pos) * 2;
    float4 P0 = part[0], P1 = part[1];
    float M = P0.x, zv = P0.y, q2v = P0.z;
    int loc = __float_as_int(P0.w);
    {
      float M1 = P1.x;
      float Mn = fmaxf(M, M1);
      float c0 = __expf(M - Mn), c1 = __expf(M1 - Mn);
      zv = zv * c0 + P1.y * c1;
      q2v = q2v * c0 * c0 + P1.z * c1 * c1;
      int loc1 = __float_as_int(P1.w);
      loc = (M1 > M) ? loc1 : ((M1 == M && loc1 < loc) ? loc1 : loc);
      M = Mn;
    }
    const int len  = side ? ll_b : rl_b;
    const int own  = side ? rl_b : ll_b;     // == plen
    const int ninv = side ? (LL - ll_b) : (RR - rl_b);
    float z0 = zv + (float)ninv * __expf(-10.f - M);
    float S = zv / z0;
    float inv = 1.f / (S + 1e-13f);
    float mean = S * inv / (float)len;
    float sumq2 = q2v / (z0 * z0) * inv * inv;
    float var = sumq2 / (float)len - mean * mean;
    ppw[t] = var / fmaxf(mean, 0.001f);
    float qmax = inv / z0;
    ppa[t] = qmax / fmaxf(qmax, 0.001f);
    ppi[t] = (pos < own && loc != 0x7fffffff) ? loc : 0;
    ppv[t] = (pos < plen) ? 1 : 0;
  }
  __syncthreads();

  const int pos  = t >> 1;
  const int half = t & 1;
  const float w_ = ppw[pos];
  const float a_ = ppa[pos];
  const int   yi = ppi[pos];
  const float* xp = x + (size_t)(s0 + pos) * BD + b * DD + half * 16;
  const float* yp = y + (size_t)yi * BD + b * DD + half * 16;

  const int asl0 = (((2 * half) ^ ((pos >> 1) & 3)) * 8);
  const int asl1 = (((2 * half + 1) ^ ((pos >> 1) & 3)) * 8);

  const int idx1 = (t < 192) ? t + 256 : t;
  const int f0 = t >> 2,   q0 = t & 3;
  const int f1 = idx1 >> 2, q1 = idx1 & 3;
  const int wsl0 = ((q0 ^ ((f0 >> 1) & 3)) * 8);
  const int wsl1 = ((q1 ^ ((f1 >> 1) & 3)) * 8);

  const int lane = t & 63;
  const int wvi = t >> 6;        // wave 0..3
  const int m0 = wvi * 32;
  const int fr = lane & 15;
  const int kh = lane >> 4;
  const int koff = (kh ^ ((fr >> 1) & 3)) * 8;

  float4 xv[4], yv[4];
  uint4 w0h, w0l, w1h, w1l;

#define LOADX(n) { const int off = ((n) < 15 ? (n) : 15) * 32; \
    xv[0] = *(const float4*)(xp + off);      xv[1] = *(const float4*)(xp + off + 4); \
    xv[2] = *(const float4*)(xp + off + 8);  xv[3] = *(const float4*)(xp + off + 12); \
    yv[0] = *(const float4*)(yp + off);      yv[1] = *(const float4*)(yp + off + 4); \
    yv[2] = *(const float4*)(yp + off + 8);  yv[3] = *(const float4*)(yp + off + 12); }

#define LOADW(n) { const int off = ((n) < 15 ? (n) : 15) * 32; \
    w0h = *(const uint4*)&Whg[f0 * DD + off + q0 * 8]; \
    w0l = *(const uint4*)&Wlg[f0 * DD + off + q0 * 8]; \
    w1h = *(const uint4*)&Whg[f1 * DD + off + q1 * 8]; \
    w1l = *(const uint4*)&Wlg[f1 * DD + off + q1 * 8]; }

#define STAGEA(nb) { \
    float d0 = w_ * fabsf(xv[0].x - a_ * yv[0].x); \
    float d1 = w_ * fabsf(xv[0].y - a_ * yv[0].y); \
    float d2 = w_ * fabsf(xv[0].z - a_ * yv[0].z); \
    float d3 = w_ * fabsf(xv[0].w - a_ * yv[0].w); \
    float d4 = w_ * fabsf(xv[1].x - a_ * yv[1].x); \
    float d5 = w_ * fabsf(xv[1].y - a_ * yv[1].y); \
    float d6 = w_ * fabsf(xv[1].z - a_ * yv[1].z); \
    float d7 = w_ * fabsf(xv[1].w - a_ * yv[1].w); \
    unsigned h01, l01, h23, l23, h45, l45, h67, l67; \
    split2(d0, d1, h01, l01); split2(d2, d3, h23, l23); \
    split2(d4, d5, h45, l45); split2(d6, d7, h67, l67); \
    *(uint4*)&Ah[nb][pos][asl0] = make_uint4(h01, h23, h45, h67); \
    *(uint4*)&Al[nb][pos][asl0] = make_uint4(l01, l23, l45, l67); \
    d0 = w_ * fabsf(xv[2].x - a_ * yv[2].x); \
    d1 = w_ * fabsf(xv[2].y - a_ * yv[2].y); \
    d2 = w_ * fabsf(xv[2].z - a_ * yv[2].z); \
    d3 = w_ * fabsf(xv[2].w - a_ * yv[2].w); \
    d4 = w_ * fabsf(xv[3].x - a_ * yv[3].x); \
    d5 = w_ * fabsf(xv[3].y - a_ * yv[3].y); \
    d6 = w_ * fabsf(xv[3].z - a_ * yv[3].z); \
    d7 = w_ * fabsf(xv[3].w - a_ * yv[3].w); \
    split2(d0, d1, h01, l01); split2(d2, d3, h23, l23); \
    split2(d4, d5, h45, l45); split2(d6, d7, h67, l67); \
    *(uint4*)&Ah[nb][pos][asl1] = make_uint4(h01, h23, h45, h67); \
    *(uint4*)&Al[nb][pos][asl1] = make_uint4(l01, l23, l45, l67); }

#define STAGEW(nb) { \
    *(uint4*)&Wh[nb][f0][wsl0] = w0h; *(uint4*)&Wl[nb][f0][wsl0] = w0l; \
    *(uint4*)&Wh[nb][f1][wsl1] = w1h; *(uint4*)&Wl[nb][f1][wsl1] = w1l; }

  // Phase with MFMA split around STAGE/LOAD: j=0..2 MFMAs, stage+load, j=3..6.
  // ah/al (16 regs) stay live across the stage — ample register headroom here.
#define PHASEC(cb, nb, n) { bf16x8 ah0, ah1, al0, al1; \
    ah0 = *(const bf16x8*)&Ah[cb][m0 + fr][koff]; \
    ah1 = *(const bf16x8*)&Ah[cb][m0 + 16 + fr][koff]; \
    al0 = *(const bf16x8*)&Al[cb][m0 + fr][koff]; \
    al1 = *(const bf16x8*)&Al[cb][m0 + 16 + fr][koff]; \
    __builtin_amdgcn_s_setprio(1); \
    _Pragma("unroll") \
    for (int j = 0; j < 3; ++j) { \
      bf16x8 bh = *(const bf16x8*)&Wh[cb][j * 16 + fr][koff]; \
      bf16x8 bl = *(const bf16x8*)&Wl[cb][j * 16 + fr][koff]; \
      acc[0][j] = __builtin_amdgcn_mfma_f32_16x16x32_bf16(ah0, bh, acc[0][j], 0, 0, 0); \
      acc[0][j] = __builtin_amdgcn_mfma_f32_16x16x32_bf16(ah0, bl, acc[0][j], 0, 0, 0); \
      acc[0][j] = __builtin_amdgcn_mfma_f32_16x16x32_bf16(al0, bh, acc[0][j], 0, 0, 0); \
      acc[1][j] = __builtin_amdgcn_mfma_f32_16x16x32_bf16(ah1, bh, acc[1][j], 0, 0, 0); \
      acc[1][j] = __builtin_amdgcn_mfma_f32_16x16x32_bf16(ah1, bl, acc[1][j], 0, 0, 0); \
      acc[1][j] = __builtin_amdgcn_mfma_f32_16x16x32_bf16(al1, bh, acc[1][j], 0, 0, 0); \
    } \
    __builtin_amdgcn_s_setprio(0); \
    STAGEA(nb); STAGEW(nb); \
    LOADX(n); LOADW(n); \
    __builtin_amdgcn_s_setprio(1); \
    _Pragma("unroll") \
    for (int j = 3; j < 7; ++j) { \
      bf16x8 bh = *(const bf16x8*)&Wh[cb][j * 16 + fr][koff]; \
      bf16x8 bl = *(const bf16x8*)&Wl[cb][j * 16 + fr][koff]; \
      acc[0][j] = __builtin_amdgcn_mfma_f32_16x16x32_bf16(ah0, bh, acc[0][j], 0, 0, 0); \
      acc[0][j] = __builtin_amdgcn_mfma_f32_16x16x32_bf16(ah0, bl, acc[0][j], 0, 0, 0); \
      acc[0][j] = __builtin_amdgcn_mfma_f32_16x16x32_bf16(al0, bh, acc[0][j], 0, 0, 0); \
      acc[1][j] = __builtin_amdgcn_mfma_f32_16x16x32_bf16(ah1, bh, acc[1][j], 0, 0, 0); \
      acc[1][j] = __builtin_amdgcn_mfma_f32_16x16x32_bf16(ah1, bl, acc[1][j], 0, 0, 0); \
      acc[1][j] = __builtin_amdgcn_mfma_f32_16x16x32_bf16(al1, bh, acc[1][j], 0, 0, 0); \
    } \
    __builtin_amdgcn_s_setprio(0); }

  f32x4 acc[2][7];
#pragma unroll
  for (int i = 0; i < 2; ++i)
#pragma unroll
    for (int j = 0; j < 7; ++j) acc[i][j] = (f32x4){0.f, 0.f, 0.f, 0.f};

  // prologue: chunk0 -> buf0; chunk1 -> regs
  LOADX(0); LOADW(0);
  STAGEA(0); STAGEW(0);
  LOADX(1); LOADW(1);
  bar_lgkm();

  for (int p2 = 0; p2 < 8; ++p2) {
    const int c = p2 * 2;
    PHASEC(0, 1, c + 2);
    bar_lgkm();
    PHASEC(1, 0, c + 3);
    bar_lgkm();
  }

  // epilogue: bias + relu + validity + maxpool
#pragma unroll
  for (int j = 0; j < 7; ++j) {
    int f = j * 16 + fr;
    float bcv = (f < FC) ? bconv[f] : 0.f;
    float vmax = -1e30f;
#pragma unroll
    for (int i = 0; i < 2; ++i) {
#pragma unroll
      for (int q = 0; q < 4; ++q) {
        int sl = m0 + i * 16 + kh * 4 + q;
        if (ppv[sl]) vmax = fmaxf(vmax, fmaxf(acc[i][j][q] + bcv, 0.f));
      }
    }
    vmax = fmaxf(vmax, __shfl_xor(vmax, 16, 64));
    vmax = fmaxf(vmax, __shfl_xor(vmax, 32, 64));
    if (lane < 16) pool[wvi][f] = vmax;
  }
  __syncthreads();
  if (t < FC) {
    float v = fmaxf(fmaxf(pool[0][t], pool[1][t]), fmaxf(pool[2][t], pool[3][t]));
    poolws[(((size_t)side * 64 + b) * 4 + (wid & 3)) * FP + t] = v;
  }
#undef LOADX
#undef LOADW
#undef STAGEA
#undef STAGEW
#undef PHASEC
}

// ---------------- final: 4-chunk pool max -> dense [200]x[200,60] + relu ----------------
__global__ __launch_bounds__(256) void dense_out(const float* __restrict__ poolws,
                          const float* __restrict__ Wd,
                          const float* __restrict__ bd, float* __restrict__ out) {
  __shared__ float fs[200];
  const int b = blockIdx.x, t = threadIdx.x;
  if (t < 200) {
    int side = t / FC, f = t - side * FC;
    const float* p = poolws + (((size_t)side * 64 + b) * 4) * FP + f;
    float v = fmaxf(fmaxf(p[0], p[FP]), fmaxf(p[2 * FP], p[3 * FP]));
    fs[t] = (v > -1e29f) ? v : 0.f;
  }
  __syncthreads();
  if (t < HH) {
    float s = bd[t];
    const float* wr = Wd + t * 200;
    for (int k = 0; k < 200; ++k) s += fs[k] * wr[k];
    out[b * HH + t] = fmaxf(s, 0.f);
  }
}

extern "C" void kernel_launch(void* const* d_in, const int* in_sizes, int n_in,
                              void* d_out, int out_size, void* d_ws, size_t ws_size,
                              hipStream_t stream) {
  (void)in_sizes; (void)n_in; (void)out_size; (void)ws_size;
  const int*   llen  = (const int*)d_in[0];
  const float* lv    = (const float*)d_in[1];
  const int*   rlen  = (const int*)d_in[2];
  const float* rv    = (const float*)d_in[3];
  const float* Wconv = (const float*)d_in[4];
  const float* bconv = (const float*)d_in[5];
  const float* Wd    = (const float*)d_in[6];
  const float* bd    = (const float*)d_in[7];
  float* out = (float*)d_out;
  char* ws = (char*)d_ws;
  size_t off = 0;
  unsigned short* Whg = (unsigned short*)(ws + off); off += (size_t)FP * DD * 2;
  unsigned short* Wlg = (unsigned short*)(ws + off); off += (size_t)FP * DD * 2;
  float4* lpart = (float4*)(ws + off); off += (size_t)BB * LL * 2 * 16;   // 1 MiB
  float4* rpart = (float4*)(ws + off); off += (size_t)BB * RR * 2 * 16;   // 1 MiB
  float* poolws = (float*)(ws + off); off += (size_t)2 * BB * 4 * FP * 4;

  prep_w<<<(FP * DD + 255) / 256, 256, 0, stream>>>(Wconv, Whg, Wlg);
  gemm_att<<<dim3(256), 512, 0, stream>>>(lv, rv, llen, rlen, lpart, rpart);
  conv_pool_mfma<<<dim3(512), 256, 0, stream>>>(lv, rv, lpart, rpart, llen, rlen,
                                                Whg, Wlg, bconv, poolws);
  dense_out<<<BB, 256, 0, stream>>>(poolws, Wd, bd, out);
}